// Round 3
// baseline (319.771 us; speedup 1.0000x reference)
//
#include <hip/hip_runtime.h>
#include <hip/hip_bf16.h>

typedef __attribute__((ext_vector_type(4))) float f32x4;
typedef __attribute__((ext_vector_type(8))) short s16x8;
typedef __attribute__((ext_vector_type(4))) short s16x4;
typedef unsigned short u16;

// ---- helpers -------------------------------------------------------------

__device__ __forceinline__ f32x4 mfma16(s16x8 a, s16x8 b, f32x4 c) {
    return __builtin_amdgcn_mfma_f32_16x16x32_bf16(a, b, c, 0, 0, 0);
}

// RNE fp32 -> bf16 (bit trick)
__device__ __forceinline__ u16 bf(float f) {
    union { float f; unsigned u; } x; x.f = f;
    return (u16)((x.u + 0x7fffu + ((x.u >> 16) & 1u)) >> 16);
}
__device__ __forceinline__ unsigned pkbf(float a, float b) {
    union { float f; unsigned u; } x, y; x.f = a; y.f = b;
    unsigned ra = x.u + 0x7fffu + ((x.u >> 16) & 1u);
    unsigned rb = y.u + 0x7fffu + ((y.u >> 16) & 1u);
    return (ra >> 16) | (rb & 0xffff0000u);
}
__device__ __forceinline__ s16x8 cvt8(f32x4 lo, f32x4 hi) {
    union { s16x8 v; unsigned u[4]; } r;
    r.u[0] = pkbf(lo.x, lo.y);
    r.u[1] = pkbf(lo.z, lo.w);
    r.u[2] = pkbf(hi.x, hi.y);
    r.u[3] = pkbf(hi.z, hi.w);
    return r.v;
}

// async global->LDS, 16B per lane (wave-uniform LDS base + lane*16)
__device__ __forceinline__ void gl_lds16(const u16* g, u16* l) {
    __builtin_amdgcn_global_load_lds(
        (const __attribute__((address_space(1))) unsigned*)g,
        (__attribute__((address_space(3))) unsigned*)l, 16, 0, 0);
}

// ---- K0: fp32 -> bf16 convert -------------------------------------------

__global__ __launch_bounds__(256) void cvt_kernel(const float* __restrict__ src,
                                                  u16* __restrict__ dst, int n4) {
    int i = blockIdx.x * 256 + threadIdx.x;
    if (i < n4) {
        f32x4 v = ((const f32x4*)src)[i];
        union { s16x4 v; unsigned u[2]; } r;
        r.u[0] = pkbf(v.x, v.y);
        r.u[1] = pkbf(v.z, v.w);
        ((s16x4*)dst)[i] = r.v;
    }
}

// ---- K1: QKV projections, m97-style LDS-staged 128x128 GEMM -------------

__global__ __launch_bounds__(256, 2) void qkv_kernel(
        const u16* __restrict__ xb, const u16* __restrict__ wb,
        const float* __restrict__ bq, const float* __restrict__ bk,
        const float* __restrict__ bv,
        u16* __restrict__ qo, u16* __restrict__ kTo, u16* __restrict__ vTo) {
    __shared__ u16 As[128 * 32];
    __shared__ u16 Bs[128 * 32];
    int bx   = blockIdx.x % 24;
    int by   = blockIdx.x / 24;
    int tid  = threadIdx.x;
    int lane = tid & 63, w = tid >> 6;
    int l15  = lane & 15, quad = lane >> 4;
    int wr   = w >> 1, wc = w & 1;

    const u16* Ag = xb + (size_t)(by * 128 + (tid >> 2)) * 1024 + (tid & 3) * 8;
    const u16* Bg = wb + (size_t)(bx * 128 + (tid >> 2)) * 1024 + (tid & 3) * 8;
    u16* Al = As + tid * 8;
    u16* Bl = Bs + tid * 8;

    const u16* abase = As + (wr * 64 + l15) * 32 + quad * 8;
    const u16* bbase = Bs + (wc * 64 + l15) * 32 + quad * 8;

    f32x4 acc[4][4] = {};
    for (int k0 = 0; k0 < 1024; k0 += 32) {
        gl_lds16(Ag + k0, Al);
        gl_lds16(Ag + 64 * 1024 + k0, Al + 64 * 32);
        gl_lds16(Bg + k0, Bl);
        gl_lds16(Bg + 64 * 1024 + k0, Bl + 64 * 32);
        __syncthreads();
        s16x8 a[4], b[4];
#pragma unroll
        for (int mi = 0; mi < 4; mi++) a[mi] = *(const s16x8*)(abase + mi * 16 * 32);
#pragma unroll
        for (int nj = 0; nj < 4; nj++) b[nj] = *(const s16x8*)(bbase + nj * 16 * 32);
#pragma unroll
        for (int mi = 0; mi < 4; mi++)
#pragma unroll
            for (int nj = 0; nj < 4; nj++) acc[mi][nj] = mfma16(a[mi], b[nj], acc[mi][nj]);
        __syncthreads();
    }

    int fblk = (bx * 128 + wc * 64) >> 6;
    int mat  = fblk >> 4, h = fblk & 15;
    const float* bias = (mat == 0) ? bq : (mat == 1 ? bk : bv);
#pragma unroll
    for (int nj = 0; nj < 4; nj++) {
        int e = nj * 16 + l15;
        float bb = bias[h * 64 + e];
#pragma unroll
        for (int mi = 0; mi < 4; mi++) {
            int n0 = by * 128 + wr * 64 + mi * 16 + quad * 4;
            f32x4 c = acc[mi][nj];
            if (mat == 0) {
                u16* p = qo + ((size_t)h * 4096 + n0) * 64 + e;
#pragma unroll
                for (int r = 0; r < 4; r++) p[(size_t)r * 64] = bf(c[r] + bb);
            } else {
                u16* p = (mat == 1 ? kTo : vTo) + ((size_t)h * 64 + e) * 4096 + n0;
                union { s16x4 v; u16 s[4]; } pk;
#pragma unroll
                for (int r = 0; r < 4; r++) pk.s[r] = bf(c[r] + bb);
                *(s16x4*)p = pk.v;
            }
        }
    }
}

// ---- K2: kp/vp = Ew @ k, Fw @ v — LDS-staged, split-K=16, fp32 atomics --
// grid: b = p*512 + h*32 + jt*16 + ks   (1024 blocks)
// block: M=128 (j rows), N=64 (e), K-chunk=256, staged in BK=32 steps.
// A (Ew/Fw fp32) loaded coalesced (128B lines), converted bf16 in-register,
// ds_write; B (kT/vT bf16) staged via global_load_lds width=16.

__global__ __launch_bounds__(256, 4) void kpvp_kernel(
        const float* __restrict__ Ew, const float* __restrict__ Fw,
        const u16* __restrict__ kT, const u16* __restrict__ vT,
        float* __restrict__ accb) {
    __shared__ u16 As[128 * 32];   // 8 KB
    __shared__ u16 Bs[64 * 32];    // 4 KB
    int b    = blockIdx.x;
    int ks   = b & 15, jt = (b >> 4) & 1, h = (b >> 5) & 15, p = b >> 9;
    int tid  = threadIdx.x;
    int lane = tid & 63, w = tid >> 6;
    int l15  = lane & 15, quad = lane >> 4;

    const float* Ab = (p ? Fw : Ew) + ((size_t)h * 256 + jt * 128) * 4096 + ks * 256;
    const u16*  Bb = (p ? vT : kT) + (size_t)h * 64 * 4096 + ks * 256;

    // A staging role: 8 threads per row (32 floats = 128 B), 32 rows/pass
    int arow = tid >> 3, acol = (tid & 7) * 4;
    const float* Ag = Ab + (size_t)arow * 4096 + acol;
    u16* Aw = As + arow * 32 + acol;
    // B staging role: 4 threads per row (32 bf16 = 64 B), 64 rows
    const u16* Bg = Bb + (size_t)(tid >> 2) * 4096 + (tid & 3) * 8;
    u16* Bl = Bs + tid * 8;

    const u16* abase = As + (w * 32 + l15) * 32 + quad * 8;
    const u16* bbase = Bs + l15 * 32 + quad * 8;

    f32x4 acc[2][4] = {};
    for (int s = 0; s < 8; s++) {
        int kk = s * 32;
        gl_lds16(Bg + kk, Bl);
#pragma unroll
        for (int ps = 0; ps < 4; ps++) {
            f32x4 v = *(const f32x4*)(Ag + (size_t)ps * 32 * 4096 + kk);
            union { s16x4 q; unsigned u[2]; } r;
            r.u[0] = pkbf(v.x, v.y);
            r.u[1] = pkbf(v.z, v.w);
            *(s16x4*)(Aw + ps * 32 * 32) = r.q;
        }
        __syncthreads();
        s16x8 a[2], bb[4];
#pragma unroll
        for (int mi = 0; mi < 2; mi++) a[mi] = *(const s16x8*)(abase + mi * 16 * 32);
#pragma unroll
        for (int nj = 0; nj < 4; nj++) bb[nj] = *(const s16x8*)(bbase + nj * 16 * 32);
#pragma unroll
        for (int mi = 0; mi < 2; mi++)
#pragma unroll
            for (int nj = 0; nj < 4; nj++) acc[mi][nj] = mfma16(a[mi], bb[nj], acc[mi][nj]);
        __syncthreads();
    }

    float* out = accb + ((size_t)(p * 16 + h) * 256 + jt * 128 + w * 32 + quad * 4) * 64;
#pragma unroll
    for (int mi = 0; mi < 2; mi++)
#pragma unroll
        for (int nj = 0; nj < 4; nj++) {
            int e = nj * 16 + l15;
#pragma unroll
            for (int r = 0; r < 4; r++)
                atomicAdd(out + (size_t)(mi * 16 + r) * 64 + e, acc[mi][nj][r]);
        }
}

// ---- K3: bias + pack: kp bf16 (pre-scaled by 1/8), vp transposed bf16 ----

__global__ __launch_bounds__(256) void packkv_kernel(
        const float* __restrict__ accb, const float* __restrict__ Eb,
        const float* __restrict__ Fb, u16* __restrict__ kp, u16* __restrict__ vpT) {
    int idx = blockIdx.x * 256 + threadIdx.x;
    int p = idx >> 18, h = (idx >> 14) & 15, j = (idx >> 6) & 255, e = idx & 63;
    float v = accb[idx];
    if (p == 0) {
        v += Eb[h * 256 + j];
        kp[((size_t)(h * 256 + j)) * 64 + e] = bf(v * 0.125f);
    } else {
        v += Fb[h * 256 + j];
        vpT[((size_t)(h * 64 + e)) * 256 + j] = bf(v);
    }
}

// ---- K4: attention: score -> softmax -> PV ------------------------------

__global__ __launch_bounds__(256) void attn_kernel(
        const u16* __restrict__ q, const u16* __restrict__ kp,
        const u16* __restrict__ vpT, u16* __restrict__ zs) {
    __shared__ u16 ps[4][16][256];
    int bm   = blockIdx.x & 63, h = blockIdx.x >> 6;
    int lane = threadIdx.x & 63, w = threadIdx.x >> 6;
    int l15  = lane & 15, quad = lane >> 4;
    int nbase = bm * 64 + w * 16;

    f32x4 s[16] = {};
    const u16* qp  = q  + ((size_t)h * 4096 + nbase + l15) * 64 + quad * 8;
    const u16* kpp = kp + ((size_t)h * 256 + l15) * 64 + quad * 8;
#pragma unroll
    for (int e0 = 0; e0 < 64; e0 += 32) {
        s16x8 a = *(const s16x8*)(qp + e0);
#pragma unroll
        for (int jt = 0; jt < 16; jt++) {
            s16x8 b = *(const s16x8*)(kpp + jt * 16 * 64 + e0);
            s[jt] = mfma16(a, b, s[jt]);
        }
    }

    float lsum[4];
#pragma unroll
    for (int r = 0; r < 4; r++) {
        float m = s[0][r];
#pragma unroll
        for (int jt = 1; jt < 16; jt++) m = fmaxf(m, s[jt][r]);
        m = fmaxf(m, __shfl_xor(m, 1));
        m = fmaxf(m, __shfl_xor(m, 2));
        m = fmaxf(m, __shfl_xor(m, 4));
        m = fmaxf(m, __shfl_xor(m, 8));
        float l = 0.f;
#pragma unroll
        for (int jt = 0; jt < 16; jt++) {
            float pv = __expf(s[jt][r] - m);
            s[jt][r] = pv;
            l += pv;
        }
        l += __shfl_xor(l, 1);
        l += __shfl_xor(l, 2);
        l += __shfl_xor(l, 4);
        l += __shfl_xor(l, 8);
        lsum[r] = l;
    }

#pragma unroll
    for (int jt = 0; jt < 16; jt++)
#pragma unroll
        for (int r = 0; r < 4; r++)
            ps[w][quad * 4 + r][jt * 16 + l15] = bf(s[jt][r]);
    __syncthreads();

    f32x4 z[4] = {};
    const u16* vp = vpT + ((size_t)h * 64 + l15) * 256 + quad * 8;
#pragma unroll
    for (int kj = 0; kj < 8; kj++) {
        s16x8 a = *(const s16x8*)&ps[w][l15][kj * 32 + quad * 8];
#pragma unroll
        for (int et = 0; et < 4; et++) {
            s16x8 b = *(const s16x8*)(vp + et * 16 * 256 + kj * 32);
            z[et] = mfma16(a, b, z[et]);
        }
    }
#pragma unroll
    for (int et = 0; et < 4; et++) {
        int e = et * 16 + l15;
        u16* o = zs + ((size_t)(nbase + quad * 4)) * 1024 + h * 64 + e;
#pragma unroll
        for (int r = 0; r < 4; r++) o[(size_t)r * 1024] = bf(z[et][r] / lsum[r]);
    }
}

// ---- K5: out = zs @ Wo^T, split-K=4 with fp32 atomics -------------------

__global__ __launch_bounds__(256) void out_kernel(
        const u16* __restrict__ zs, const u16* __restrict__ wob,
        float* __restrict__ out) {
    int ks   = blockIdx.x & 3;
    int bm   = blockIdx.x >> 2;
    int lane = threadIdx.x & 63, w = threadIdx.x >> 6;
    int l15  = lane & 15, quad = lane >> 4;
    int row0 = bm * 128 + w * 32;

    const u16* A = zs  + (size_t)(row0 + l15) * 1024 + ks * 256 + quad * 8;
    const u16* B = wob + (size_t)l15 * 1024 + ks * 256 + quad * 8;

    f32x4 acc[2][4] = {};
    for (int k = 0; k < 256; k += 32) {
        s16x8 a0 = *(const s16x8*)(A + k);
        s16x8 a1 = *(const s16x8*)(A + 16 * 1024 + k);
#pragma unroll
        for (int nt = 0; nt < 4; nt++) {
            s16x8 bv = *(const s16x8*)(B + (size_t)nt * 16 * 1024 + k);
            acc[0][nt] = mfma16(a0, bv, acc[0][nt]);
            acc[1][nt] = mfma16(a1, bv, acc[1][nt]);
        }
    }
#pragma unroll
    for (int mt = 0; mt < 2; mt++)
#pragma unroll
        for (int nt = 0; nt < 4; nt++) {
            int e = nt * 16 + l15;
            int n0 = row0 + mt * 16 + quad * 4;
            float* o = out + (size_t)n0 * 64 + e;
#pragma unroll
            for (int r = 0; r < 4; r++) atomicAdd(o + (size_t)r * 64, acc[mt][nt][r]);
        }
}

// ---- launch --------------------------------------------------------------

extern "C" void kernel_launch(void* const* d_in, const int* in_sizes, int n_in,
                              void* d_out, int out_size, void* d_ws, size_t ws_size,
                              hipStream_t stream) {
    const float* x  = (const float*)d_in[0];
    const float* Wq = (const float*)d_in[1];
    const float* bq = (const float*)d_in[2];
    const float* Wk = (const float*)d_in[3];
    const float* bk = (const float*)d_in[4];
    const float* Wv = (const float*)d_in[5];
    const float* bv = (const float*)d_in[6];
    const float* Ew = (const float*)d_in[7];
    const float* Eb = (const float*)d_in[8];
    const float* Fw = (const float*)d_in[9];
    const float* Fb = (const float*)d_in[10];
    const float* Wo = (const float*)d_in[11];

    char* ws = (char*)d_ws;
    u16*   qb   = (u16*)(ws + 0);          // H*N*E bf16            8 MB
    u16*   kT   = (u16*)(ws + 8388608);    // H*E*N bf16            8 MB
    u16*   vT   = (u16*)(ws + 16777216);   // H*E*N bf16            8 MB
    u16*   zsb  = (u16*)(ws + 25165824);   // N*(H*E) bf16          8 MB
    float* accb = (float*)(ws + 33554432); // 2*H*256*64 fp32       2 MB
    u16*   kp   = (u16*)(ws + 35651584);   // H*256*64 bf16       0.5 MB
    u16*   vpT  = (u16*)(ws + 36175872);   // H*64*256 bf16       0.5 MB
    u16*   xb   = (u16*)(ws + 36700160);   // N*D bf16              8 MB
    u16*   wb   = (u16*)(ws + 45088768);   // 3*H*E*D bf16          6 MB
    u16*   wob  = (u16*)(ws + 51380224);   // E*(H*E) bf16       128 KB

    hipMemsetAsync(accb, 0, (size_t)2 * 16 * 256 * 64 * sizeof(float), stream);
    hipMemsetAsync(d_out, 0, (size_t)4096 * 64 * sizeof(float), stream);

    cvt_kernel<<<4096, 256, 0, stream>>>(x,  xb, 1048576);
    cvt_kernel<<<1024, 256, 0, stream>>>(Wq, wb,           262144);
    cvt_kernel<<<1024, 256, 0, stream>>>(Wk, wb + 1048576, 262144);
    cvt_kernel<<<1024, 256, 0, stream>>>(Wv, wb + 2097152, 262144);
    cvt_kernel<<<64,   256, 0, stream>>>(Wo, wob, 16384);

    qkv_kernel<<<768, 256, 0, stream>>>(xb, wb, bq, bk, bv, qb, kT, vT);
    kpvp_kernel<<<1024, 256, 0, stream>>>(Ew, Fw, kT, vT, accb);
    packkv_kernel<<<2048, 256, 0, stream>>>(accb, Eb, Fb, kp, vpT);
    attn_kernel<<<1024, 256, 0, stream>>>(qb, kp, vpT, zsb);
    out_kernel<<<128, 256, 0, stream>>>(zsb, wob, (float*)d_out);
}

// Round 4
// 313.163 us; speedup vs baseline: 1.0211x; 1.0211x over previous
//
#include <hip/hip_runtime.h>
#include <hip/hip_bf16.h>

typedef __attribute__((ext_vector_type(4))) float f32x4;
typedef __attribute__((ext_vector_type(8))) short s16x8;
typedef __attribute__((ext_vector_type(4))) short s16x4;
typedef unsigned short u16;

// ---- helpers -------------------------------------------------------------

__device__ __forceinline__ f32x4 mfma16(s16x8 a, s16x8 b, f32x4 c) {
    return __builtin_amdgcn_mfma_f32_16x16x32_bf16(a, b, c, 0, 0, 0);
}

// RNE fp32 -> bf16 (bit trick)
__device__ __forceinline__ u16 bf(float f) {
    union { float f; unsigned u; } x; x.f = f;
    return (u16)((x.u + 0x7fffu + ((x.u >> 16) & 1u)) >> 16);
}
__device__ __forceinline__ unsigned pkbf(float a, float b) {
    union { float f; unsigned u; } x, y; x.f = a; y.f = b;
    unsigned ra = x.u + 0x7fffu + ((x.u >> 16) & 1u);
    unsigned rb = y.u + 0x7fffu + ((y.u >> 16) & 1u);
    return (ra >> 16) | (rb & 0xffff0000u);
}
__device__ __forceinline__ s16x8 cvt8(f32x4 lo, f32x4 hi) {
    union { s16x8 v; unsigned u[4]; } r;
    r.u[0] = pkbf(lo.x, lo.y);
    r.u[1] = pkbf(lo.z, lo.w);
    r.u[2] = pkbf(hi.x, hi.y);
    r.u[3] = pkbf(hi.z, hi.w);
    return r.v;
}

// async global->LDS, 16B per lane (wave-uniform LDS base + lane*16)
__device__ __forceinline__ void gl_lds16(const u16* g, u16* l) {
    __builtin_amdgcn_global_load_lds(
        (const __attribute__((address_space(1))) unsigned*)g,
        (__attribute__((address_space(3))) unsigned*)l, 16, 0, 0);
}

// ---- K0: fp32 -> bf16 convert -------------------------------------------

__global__ __launch_bounds__(256) void cvt_kernel(const float* __restrict__ src,
                                                  u16* __restrict__ dst, int n4) {
    int i = blockIdx.x * 256 + threadIdx.x;
    if (i < n4) {
        f32x4 v = ((const f32x4*)src)[i];
        union { s16x4 v; unsigned u[2]; } r;
        r.u[0] = pkbf(v.x, v.y);
        r.u[1] = pkbf(v.z, v.w);
        ((s16x4*)dst)[i] = r.v;
    }
}

// ---- K1: QKV projections, m97-style LDS-staged 128x128 GEMM -------------

__global__ __launch_bounds__(256, 2) void qkv_kernel(
        const u16* __restrict__ xb, const u16* __restrict__ wb,
        const float* __restrict__ bq, const float* __restrict__ bk,
        const float* __restrict__ bv,
        u16* __restrict__ qo, u16* __restrict__ kTo, u16* __restrict__ vTo) {
    __shared__ u16 As[128 * 32];
    __shared__ u16 Bs[128 * 32];
    int bx   = blockIdx.x % 24;
    int by   = blockIdx.x / 24;
    int tid  = threadIdx.x;
    int lane = tid & 63, w = tid >> 6;
    int l15  = lane & 15, quad = lane >> 4;
    int wr   = w >> 1, wc = w & 1;

    const u16* Ag = xb + (size_t)(by * 128 + (tid >> 2)) * 1024 + (tid & 3) * 8;
    const u16* Bg = wb + (size_t)(bx * 128 + (tid >> 2)) * 1024 + (tid & 3) * 8;
    u16* Al = As + tid * 8;
    u16* Bl = Bs + tid * 8;

    const u16* abase = As + (wr * 64 + l15) * 32 + quad * 8;
    const u16* bbase = Bs + (wc * 64 + l15) * 32 + quad * 8;

    f32x4 acc[4][4] = {};
    for (int k0 = 0; k0 < 1024; k0 += 32) {
        gl_lds16(Ag + k0, Al);
        gl_lds16(Ag + 64 * 1024 + k0, Al + 64 * 32);
        gl_lds16(Bg + k0, Bl);
        gl_lds16(Bg + 64 * 1024 + k0, Bl + 64 * 32);
        __syncthreads();
        s16x8 a[4], b[4];
#pragma unroll
        for (int mi = 0; mi < 4; mi++) a[mi] = *(const s16x8*)(abase + mi * 16 * 32);
#pragma unroll
        for (int nj = 0; nj < 4; nj++) b[nj] = *(const s16x8*)(bbase + nj * 16 * 32);
#pragma unroll
        for (int mi = 0; mi < 4; mi++)
#pragma unroll
            for (int nj = 0; nj < 4; nj++) acc[mi][nj] = mfma16(a[mi], b[nj], acc[mi][nj]);
        __syncthreads();
    }

    int fblk = (bx * 128 + wc * 64) >> 6;
    int mat  = fblk >> 4, h = fblk & 15;
    const float* bias = (mat == 0) ? bq : (mat == 1 ? bk : bv);
#pragma unroll
    for (int nj = 0; nj < 4; nj++) {
        int e = nj * 16 + l15;
        float bb = bias[h * 64 + e];
#pragma unroll
        for (int mi = 0; mi < 4; mi++) {
            int n0 = by * 128 + wr * 64 + mi * 16 + quad * 4;
            f32x4 c = acc[mi][nj];
            if (mat == 0) {
                u16* p = qo + ((size_t)h * 4096 + n0) * 64 + e;
#pragma unroll
                for (int r = 0; r < 4; r++) p[(size_t)r * 64] = bf(c[r] + bb);
            } else {
                u16* p = (mat == 1 ? kTo : vTo) + ((size_t)h * 64 + e) * 4096 + n0;
                union { s16x4 v; u16 s[4]; } pk;
#pragma unroll
                for (int r = 0; r < 4; r++) pk.s[r] = bf(c[r] + bb);
                *(s16x4*)p = pk.v;
            }
        }
    }
}

// ---- K2: kp/vp = Ew @ k, Fw @ v — dbuf LDS pipeline, split-K=4, NO atomics
// grid: b = p*512 + h*32 + jt*4 + ks   (1024 blocks, 4/CU)
// block: M=32 (j rows), N=64 (e), K-chunk=1024, BK=64 double-buffered.
// Output: 4 disjoint fp32 slices accs[ks][p][h][j][e], plain stores.

__global__ __launch_bounds__(256, 4) void kpvp_kernel(
        const float* __restrict__ Ew, const float* __restrict__ Fw,
        const u16* __restrict__ kT, const u16* __restrict__ vT,
        float* __restrict__ accs) {
    __shared__ u16 As[2][32 * 72];   // 32 rows x 64 k (+8 pad), bf16
    __shared__ u16 Bs[2][8192];      // 64 e x 64 k, gl_lds natural layout
    int b    = blockIdx.x;
    int ks   = b & 3, jt = (b >> 2) & 7, h = (b >> 5) & 15, p = b >> 9;
    int tid  = threadIdx.x;
    int lane = tid & 63, w = tid >> 6;
    int l15  = lane & 15, quad = lane >> 4;
    int wm   = w & 1, wn = w >> 1;

    // A: coalesced row-chunk loads. thread t: row t>>3 (32), 8 fp32 at col (t&7)*8
    const float* Ag = (p ? Fw : Ew) +
        ((size_t)(h * 256 + jt * 32) + (tid >> 3)) * 4096 + ks * 1024 + (tid & 7) * 8;
    // B: gl_lds: thread t: e-row t>>2 (64), 8 bf16 at n-chunk (t&3)*8
    const u16* Bg = (p ? vT : kT) +
        ((size_t)h * 64 + (tid >> 2)) * 4096 + ks * 1024 + (tid & 3) * 8;

    u16* Aw[2] = { &As[0][(tid >> 3) * 72 + (tid & 7) * 8],
                   &As[1][(tid >> 3) * 72 + (tid & 7) * 8] };
    u16* Bw[2] = { &Bs[0][tid * 8], &Bs[1][tid * 8] };

    // prologue: stage 0 into buf 0
    gl_lds16(Bg, Bw[0]);
    gl_lds16(Bg + 32, Bw[0] + 4096);
    {
        f32x4 a0 = *(const f32x4*)(Ag);
        f32x4 a1 = *(const f32x4*)(Ag + 4);
        *(s16x8*)Aw[0] = cvt8(a0, a1);
    }

    const u16* abase = &As[0][(wm * 16 + l15) * 72 + quad * 8];
    const u16* bbase = &Bs[0][(wn * 32 + l15) * 32 + quad * 8];

    f32x4 acc[2] = {};
    for (int s = 0; s < 16; s++) {
        __syncthreads();   // stage s data visible; stage s-1 reads done
        int cur = s & 1, nxt = cur ^ 1;
        f32x4 a0, a1;
        if (s < 15) {      // prefetch stage s+1 into other buffer
            gl_lds16(Bg + (s + 1) * 64, Bw[nxt]);
            gl_lds16(Bg + (s + 1) * 64 + 32, Bw[nxt] + 4096);
            a0 = *(const f32x4*)(Ag + (s + 1) * 64);
            a1 = *(const f32x4*)(Ag + (s + 1) * 64 + 4);
        }
        // compute stage s from buf cur (LDS only -> lgkmcnt, overlaps vmem)
        const u16* ab = abase + cur * (32 * 72);
        const u16* bb = bbase + cur * 8192;
#pragma unroll
        for (int kstep = 0; kstep < 2; kstep++) {
            s16x8 af = *(const s16x8*)(ab + kstep * 32);
#pragma unroll
            for (int nt = 0; nt < 2; nt++) {
                s16x8 bfr = *(const s16x8*)(bb + kstep * 4096 + nt * 16 * 32);
                acc[nt] = mfma16(af, bfr, acc[nt]);
            }
        }
        if (s < 15) {      // convert+write A after compute (hide vm latency)
            *(s16x8*)Aw[nxt] = cvt8(a0, a1);
        }
    }

    // plain stores to this block's disjoint slice
    size_t base = (size_t)ks * 524288 +
        ((size_t)(p * 16 + h) * 256 + jt * 32 + wm * 16 + quad * 4) * 64 + wn * 32 + l15;
#pragma unroll
    for (int nt = 0; nt < 2; nt++)
#pragma unroll
        for (int r = 0; r < 4; r++)
            accs[base + (size_t)r * 64 + nt * 16] = acc[nt][r];
}

// ---- K3: reduce 4 slices + bias + pack ----------------------------------

__global__ __launch_bounds__(256) void packkv_kernel(
        const float* __restrict__ accs, const float* __restrict__ Eb,
        const float* __restrict__ Fb, u16* __restrict__ kp, u16* __restrict__ vpT) {
    int idx = blockIdx.x * 256 + threadIdx.x;
    float v = accs[idx] + accs[idx + 524288] + accs[idx + 1048576] + accs[idx + 1572864];
    int p = idx >> 18, h = (idx >> 14) & 15, j = (idx >> 6) & 255, e = idx & 63;
    if (p == 0) {
        v += Eb[h * 256 + j];
        kp[((size_t)(h * 256 + j)) * 64 + e] = bf(v * 0.125f);  // fold 1/sqrt(64)
    } else {
        v += Fb[h * 256 + j];
        vpT[((size_t)(h * 64 + e)) * 256 + j] = bf(v);
    }
}

// ---- K4: attention: score -> softmax -> PV ------------------------------

__global__ __launch_bounds__(256) void attn_kernel(
        const u16* __restrict__ q, const u16* __restrict__ kp,
        const u16* __restrict__ vpT, u16* __restrict__ zs) {
    __shared__ u16 ps[4][16][256];
    int bm   = blockIdx.x & 63, h = blockIdx.x >> 6;
    int lane = threadIdx.x & 63, w = threadIdx.x >> 6;
    int l15  = lane & 15, quad = lane >> 4;
    int nbase = bm * 64 + w * 16;

    f32x4 s[16] = {};
    const u16* qp  = q  + ((size_t)h * 4096 + nbase + l15) * 64 + quad * 8;
    const u16* kpp = kp + ((size_t)h * 256 + l15) * 64 + quad * 8;
#pragma unroll
    for (int e0 = 0; e0 < 64; e0 += 32) {
        s16x8 a = *(const s16x8*)(qp + e0);
#pragma unroll
        for (int jt = 0; jt < 16; jt++) {
            s16x8 b = *(const s16x8*)(kpp + jt * 16 * 64 + e0);
            s[jt] = mfma16(a, b, s[jt]);
        }
    }

    float lsum[4];
#pragma unroll
    for (int r = 0; r < 4; r++) {
        float m = s[0][r];
#pragma unroll
        for (int jt = 1; jt < 16; jt++) m = fmaxf(m, s[jt][r]);
        m = fmaxf(m, __shfl_xor(m, 1));
        m = fmaxf(m, __shfl_xor(m, 2));
        m = fmaxf(m, __shfl_xor(m, 4));
        m = fmaxf(m, __shfl_xor(m, 8));
        float l = 0.f;
#pragma unroll
        for (int jt = 0; jt < 16; jt++) {
            float pv = __expf(s[jt][r] - m);
            s[jt][r] = pv;
            l += pv;
        }
        l += __shfl_xor(l, 1);
        l += __shfl_xor(l, 2);
        l += __shfl_xor(l, 4);
        l += __shfl_xor(l, 8);
        lsum[r] = l;
    }

#pragma unroll
    for (int jt = 0; jt < 16; jt++)
#pragma unroll
        for (int r = 0; r < 4; r++)
            ps[w][quad * 4 + r][jt * 16 + l15] = bf(s[jt][r]);
    __syncthreads();

    f32x4 z[4] = {};
    const u16* vp = vpT + ((size_t)h * 64 + l15) * 256 + quad * 8;
#pragma unroll
    for (int kj = 0; kj < 8; kj++) {
        s16x8 a = *(const s16x8*)&ps[w][l15][kj * 32 + quad * 8];
#pragma unroll
        for (int et = 0; et < 4; et++) {
            s16x8 b = *(const s16x8*)(vp + et * 16 * 256 + kj * 32);
            z[et] = mfma16(a, b, z[et]);
        }
    }
#pragma unroll
    for (int et = 0; et < 4; et++) {
        int e = et * 16 + l15;
        u16* o = zs + ((size_t)(nbase + quad * 4)) * 1024 + h * 64 + e;
#pragma unroll
        for (int r = 0; r < 4; r++) o[(size_t)r * 1024] = bf(z[et][r] / lsum[r]);
    }
}

// ---- K5: out = zs @ Wo^T, split-K=4 with fp32 atomics -------------------

__global__ __launch_bounds__(256) void out_kernel(
        const u16* __restrict__ zs, const u16* __restrict__ wob,
        float* __restrict__ out) {
    int ks   = blockIdx.x & 3;
    int bm   = blockIdx.x >> 2;
    int lane = threadIdx.x & 63, w = threadIdx.x >> 6;
    int l15  = lane & 15, quad = lane >> 4;
    int row0 = bm * 128 + w * 32;

    const u16* A = zs  + (size_t)(row0 + l15) * 1024 + ks * 256 + quad * 8;
    const u16* B = wob + (size_t)l15 * 1024 + ks * 256 + quad * 8;

    f32x4 acc[2][4] = {};
    for (int k = 0; k < 256; k += 32) {
        s16x8 a0 = *(const s16x8*)(A + k);
        s16x8 a1 = *(const s16x8*)(A + 16 * 1024 + k);
#pragma unroll
        for (int nt = 0; nt < 4; nt++) {
            s16x8 bv = *(const s16x8*)(B + (size_t)nt * 16 * 1024 + k);
            acc[0][nt] = mfma16(a0, bv, acc[0][nt]);
            acc[1][nt] = mfma16(a1, bv, acc[1][nt]);
        }
    }
#pragma unroll
    for (int mt = 0; mt < 2; mt++)
#pragma unroll
        for (int nt = 0; nt < 4; nt++) {
            int e = nt * 16 + l15;
            int n0 = row0 + mt * 16 + quad * 4;
            float* o = out + (size_t)n0 * 64 + e;
#pragma unroll
            for (int r = 0; r < 4; r++) atomicAdd(o + (size_t)r * 64, acc[mt][nt][r]);
        }
}

// ---- launch --------------------------------------------------------------

extern "C" void kernel_launch(void* const* d_in, const int* in_sizes, int n_in,
                              void* d_out, int out_size, void* d_ws, size_t ws_size,
                              hipStream_t stream) {
    const float* x  = (const float*)d_in[0];
    const float* Wq = (const float*)d_in[1];
    const float* bq = (const float*)d_in[2];
    const float* Wk = (const float*)d_in[3];
    const float* bk = (const float*)d_in[4];
    const float* Wv = (const float*)d_in[5];
    const float* bv = (const float*)d_in[6];
    const float* Ew = (const float*)d_in[7];
    const float* Eb = (const float*)d_in[8];
    const float* Fw = (const float*)d_in[9];
    const float* Fb = (const float*)d_in[10];
    const float* Wo = (const float*)d_in[11];

    char* ws = (char*)d_ws;
    u16*   qb   = (u16*)(ws + 0);          // H*N*E bf16            8 MB
    u16*   kT   = (u16*)(ws + 8388608);    // H*E*N bf16            8 MB
    u16*   vT   = (u16*)(ws + 16777216);   // H*E*N bf16            8 MB
    u16*   zsb  = (u16*)(ws + 25165824);   // N*(H*E) bf16          8 MB
    float* accs = (float*)(ws + 33554432); // 4 slices x 2 MB fp32  8 MB
    u16*   kp   = (u16*)(ws + 41943040);   // H*256*64 bf16       0.5 MB
    u16*   vpT  = (u16*)(ws + 42467328);   // H*64*256 bf16       0.5 MB
    u16*   xb   = (u16*)(ws + 42991616);   // N*D bf16              8 MB
    u16*   wb   = (u16*)(ws + 51380224);   // 3*H*E*D bf16          6 MB
    u16*   wob  = (u16*)(ws + 57671680);   // E*(H*E) bf16       128 KB

    hipMemsetAsync(d_out, 0, (size_t)4096 * 64 * sizeof(float), stream);

    cvt_kernel<<<4096, 256, 0, stream>>>(x,  xb, 1048576);
    cvt_kernel<<<1024, 256, 0, stream>>>(Wq, wb,           262144);
    cvt_kernel<<<1024, 256, 0, stream>>>(Wk, wb + 1048576, 262144);
    cvt_kernel<<<1024, 256, 0, stream>>>(Wv, wb + 2097152, 262144);
    cvt_kernel<<<64,   256, 0, stream>>>(Wo, wob, 16384);

    qkv_kernel<<<768, 256, 0, stream>>>(xb, wb, bq, bk, bv, qb, kT, vT);
    kpvp_kernel<<<1024, 256, 0, stream>>>(Ew, Fw, kT, vT, accs);
    packkv_kernel<<<2048, 256, 0, stream>>>(accs, Eb, Fb, kp, vpT);
    attn_kernel<<<1024, 256, 0, stream>>>(qb, kp, vpT, zsb);
    out_kernel<<<128, 256, 0, stream>>>(zsb, wob, (float*)d_out);
}

// Round 5
// 311.308 us; speedup vs baseline: 1.0272x; 1.0060x over previous
//
#include <hip/hip_runtime.h>
#include <hip/hip_bf16.h>

typedef __attribute__((ext_vector_type(4))) float f32x4;
typedef __attribute__((ext_vector_type(8))) short s16x8;
typedef __attribute__((ext_vector_type(4))) short s16x4;
typedef unsigned short u16;

// ---- helpers -------------------------------------------------------------

__device__ __forceinline__ f32x4 mfma16(s16x8 a, s16x8 b, f32x4 c) {
    return __builtin_amdgcn_mfma_f32_16x16x32_bf16(a, b, c, 0, 0, 0);
}

// RNE fp32 -> bf16 (bit trick)
__device__ __forceinline__ u16 bf(float f) {
    union { float f; unsigned u; } x; x.f = f;
    return (u16)((x.u + 0x7fffu + ((x.u >> 16) & 1u)) >> 16);
}
__device__ __forceinline__ unsigned pkbf(float a, float b) {
    union { float f; unsigned u; } x, y; x.f = a; y.f = b;
    unsigned ra = x.u + 0x7fffu + ((x.u >> 16) & 1u);
    unsigned rb = y.u + 0x7fffu + ((y.u >> 16) & 1u);
    return (ra >> 16) | (rb & 0xffff0000u);
}
__device__ __forceinline__ s16x8 cvt8(f32x4 lo, f32x4 hi) {
    union { s16x8 v; unsigned u[4]; } r;
    r.u[0] = pkbf(lo.x, lo.y);
    r.u[1] = pkbf(lo.z, lo.w);
    r.u[2] = pkbf(hi.x, hi.y);
    r.u[3] = pkbf(hi.z, hi.w);
    return r.v;
}

// async global->LDS, 16B per lane (wave-uniform LDS base + lane*16)
__device__ __forceinline__ void gl_lds16(const u16* g, u16* l) {
    __builtin_amdgcn_global_load_lds(
        (const __attribute__((address_space(1))) unsigned*)g,
        (__attribute__((address_space(3))) unsigned*)l, 16, 0, 0);
}

// ---- K0: fp32 -> bf16 convert -------------------------------------------

__global__ __launch_bounds__(256) void cvt_kernel(const float* __restrict__ src,
                                                  u16* __restrict__ dst, int n4) {
    int i = blockIdx.x * 256 + threadIdx.x;
    if (i < n4) {
        f32x4 v = ((const f32x4*)src)[i];
        union { s16x4 v; unsigned u[2]; } r;
        r.u[0] = pkbf(v.x, v.y);
        r.u[1] = pkbf(v.z, v.w);
        ((s16x4*)dst)[i] = r.v;
    }
}

// ---- K1: QKV projections, m97-style LDS-staged 128x128 GEMM -------------
// launch_bounds(256,3): 3 blocks/CU resident (grid 768 = 3/CU exactly);
// (256,2) was capping residency and latency overlap.

__global__ __launch_bounds__(256, 3) void qkv_kernel(
        const u16* __restrict__ xb, const u16* __restrict__ wb,
        const float* __restrict__ bq, const float* __restrict__ bk,
        const float* __restrict__ bv,
        u16* __restrict__ qo, u16* __restrict__ kTo, u16* __restrict__ vTo) {
    __shared__ u16 As[128 * 32];
    __shared__ u16 Bs[128 * 32];
    int bx   = blockIdx.x % 24;
    int by   = blockIdx.x / 24;
    int tid  = threadIdx.x;
    int lane = tid & 63, w = tid >> 6;
    int l15  = lane & 15, quad = lane >> 4;
    int wr   = w >> 1, wc = w & 1;

    const u16* Ag = xb + (size_t)(by * 128 + (tid >> 2)) * 1024 + (tid & 3) * 8;
    const u16* Bg = wb + (size_t)(bx * 128 + (tid >> 2)) * 1024 + (tid & 3) * 8;
    u16* Al = As + tid * 8;
    u16* Bl = Bs + tid * 8;

    const u16* abase = As + (wr * 64 + l15) * 32 + quad * 8;
    const u16* bbase = Bs + (wc * 64 + l15) * 32 + quad * 8;

    f32x4 acc[4][4] = {};
    for (int k0 = 0; k0 < 1024; k0 += 32) {
        gl_lds16(Ag + k0, Al);
        gl_lds16(Ag + 64 * 1024 + k0, Al + 64 * 32);
        gl_lds16(Bg + k0, Bl);
        gl_lds16(Bg + 64 * 1024 + k0, Bl + 64 * 32);
        __syncthreads();
        s16x8 a[4], b[4];
#pragma unroll
        for (int mi = 0; mi < 4; mi++) a[mi] = *(const s16x8*)(abase + mi * 16 * 32);
#pragma unroll
        for (int nj = 0; nj < 4; nj++) b[nj] = *(const s16x8*)(bbase + nj * 16 * 32);
#pragma unroll
        for (int mi = 0; mi < 4; mi++)
#pragma unroll
            for (int nj = 0; nj < 4; nj++) acc[mi][nj] = mfma16(a[mi], b[nj], acc[mi][nj]);
        __syncthreads();
    }

    int fblk = (bx * 128 + wc * 64) >> 6;
    int mat  = fblk >> 4, h = fblk & 15;
    const float* bias = (mat == 0) ? bq : (mat == 1 ? bk : bv);
#pragma unroll
    for (int nj = 0; nj < 4; nj++) {
        int e = nj * 16 + l15;
        float bb = bias[h * 64 + e];
#pragma unroll
        for (int mi = 0; mi < 4; mi++) {
            int n0 = by * 128 + wr * 64 + mi * 16 + quad * 4;
            f32x4 c = acc[mi][nj];
            if (mat == 0) {
                u16* p = qo + ((size_t)h * 4096 + n0) * 64 + e;
#pragma unroll
                for (int r = 0; r < 4; r++) p[(size_t)r * 64] = bf(c[r] + bb);
            } else {
                u16* p = (mat == 1 ? kTo : vTo) + ((size_t)h * 64 + e) * 4096 + n0;
                union { s16x4 v; u16 s[4]; } pk;
#pragma unroll
                for (int r = 0; r < 4; r++) pk.s[r] = bf(c[r] + bb);
                *(s16x4*)p = pk.v;
            }
        }
    }
}

// ---- K2: kp/vp = Ew @ k, Fw @ v — qkv-shaped tiles, split-K=16, no atomics
// grid: b = ((p*16+h)*2 + jt)*16 + ks  (1024 blocks, 4/CU)
// block: M=128 (j), N=64 (e), K-chunk=256 in 8 stages of BK=32.
// A (fp32) staged coalesced (8 lanes per 128B row-chunk) + cvt + ds_write
// into pad-40 rows (conflict-free a-frag reads); B via gl_lds16.
// Output: 16 disjoint fp32 slices, plain stores; packkv reduces.

__global__ __launch_bounds__(256, 4) void kpvp_kernel(
        const float* __restrict__ Ew, const float* __restrict__ Fw,
        const u16* __restrict__ kT, const u16* __restrict__ vT,
        float* __restrict__ accs) {
    __shared__ u16 As[128 * 40];   // 10 KB (pitch 40 u16 = conflict-free)
    __shared__ u16 Bs[64 * 32];    // 4 KB
    int b    = blockIdx.x;
    int ks   = b & 15, jt = (b >> 4) & 1, h = (b >> 5) & 15, p = b >> 9;
    int tid  = threadIdx.x;
    int lane = tid & 63, w = tid >> 6;
    int l15  = lane & 15, quad = lane >> 4;
    int wm   = w & 1, wn = w >> 1;

    // A: lane covers one f32x4 of a 128B row-chunk; 8 lanes/row, 4 row-passes
    const float* Ag = (p ? Fw : Ew)
        + (size_t)(h * 256 + jt * 128 + (tid >> 3)) * 4096 + ks * 256 + (tid & 7) * 4;
    // B: 4 lanes/e-row, 16B each
    const u16* Bg = (p ? vT : kT)
        + ((size_t)h * 64 + (tid >> 2)) * 4096 + ks * 256 + (tid & 3) * 8;
    u16* Aw = As + (tid >> 3) * 40 + (tid & 7) * 4;
    u16* Bl = Bs + tid * 8;

    const u16* abase = As + (wm * 64 + l15) * 40 + quad * 8;
    const u16* bbase = Bs + (wn * 32 + l15) * 32 + quad * 8;

    f32x4 acc[4][2] = {};
    for (int s = 0; s < 8; s++) {
        int kk = s * 32;
        gl_lds16(Bg + kk, Bl);
#pragma unroll
        for (int pr = 0; pr < 4; pr++) {
            f32x4 v = *(const f32x4*)(Ag + (size_t)pr * 32 * 4096 + kk);
            union { s16x4 q; unsigned u[2]; } rr;
            rr.u[0] = pkbf(v.x, v.y);
            rr.u[1] = pkbf(v.z, v.w);
            *(s16x4*)(Aw + pr * 32 * 40) = rr.q;
        }
        __syncthreads();
        s16x8 a[4], bb2[2];
#pragma unroll
        for (int mt = 0; mt < 4; mt++) a[mt] = *(const s16x8*)(abase + mt * 16 * 40);
#pragma unroll
        for (int nt = 0; nt < 2; nt++) bb2[nt] = *(const s16x8*)(bbase + nt * 16 * 32);
#pragma unroll
        for (int mt = 0; mt < 4; mt++)
#pragma unroll
            for (int nt = 0; nt < 2; nt++)
                acc[mt][nt] = mfma16(a[mt], bb2[nt], acc[mt][nt]);
        __syncthreads();
    }

    size_t base = (size_t)ks * 524288
        + ((size_t)(p * 16 + h) * 256 + jt * 128 + wm * 64 + quad * 4) * 64
        + wn * 32 + l15;
#pragma unroll
    for (int mt = 0; mt < 4; mt++)
#pragma unroll
        for (int nt = 0; nt < 2; nt++)
#pragma unroll
            for (int r = 0; r < 4; r++)
                accs[base + (size_t)(mt * 16 + r) * 64 + nt * 16] = acc[mt][nt][r];
}

// ---- K3: reduce 16 slices + bias + pack ---------------------------------

__global__ __launch_bounds__(256) void packkv_kernel(
        const float* __restrict__ accs, const float* __restrict__ Eb,
        const float* __restrict__ Fb, u16* __restrict__ kp, u16* __restrict__ vpT) {
    int idx = blockIdx.x * 256 + threadIdx.x;
    float v = 0.f;
#pragma unroll
    for (int s = 0; s < 16; s++) v += accs[idx + (size_t)s * 524288];
    int p = idx >> 18, h = (idx >> 14) & 15, j = (idx >> 6) & 255, e = idx & 63;
    if (p == 0) {
        v += Eb[h * 256 + j];
        kp[((size_t)(h * 256 + j)) * 64 + e] = bf(v * 0.125f);  // fold 1/sqrt(64)
    } else {
        v += Fb[h * 256 + j];
        vpT[((size_t)(h * 64 + e)) * 256 + j] = bf(v);
    }
}

// ---- K4: attention: score -> softmax -> PV ------------------------------

__global__ __launch_bounds__(256) void attn_kernel(
        const u16* __restrict__ q, const u16* __restrict__ kp,
        const u16* __restrict__ vpT, u16* __restrict__ zs) {
    __shared__ u16 ps[4][16][256];
    int bm   = blockIdx.x & 63, h = blockIdx.x >> 6;
    int lane = threadIdx.x & 63, w = threadIdx.x >> 6;
    int l15  = lane & 15, quad = lane >> 4;
    int nbase = bm * 64 + w * 16;

    f32x4 s[16] = {};
    const u16* qp  = q  + ((size_t)h * 4096 + nbase + l15) * 64 + quad * 8;
    const u16* kpp = kp + ((size_t)h * 256 + l15) * 64 + quad * 8;
#pragma unroll
    for (int e0 = 0; e0 < 64; e0 += 32) {
        s16x8 a = *(const s16x8*)(qp + e0);
#pragma unroll
        for (int jt = 0; jt < 16; jt++) {
            s16x8 b = *(const s16x8*)(kpp + jt * 16 * 64 + e0);
            s[jt] = mfma16(a, b, s[jt]);
        }
    }

    float lsum[4];
#pragma unroll
    for (int r = 0; r < 4; r++) {
        float m = s[0][r];
#pragma unroll
        for (int jt = 1; jt < 16; jt++) m = fmaxf(m, s[jt][r]);
        m = fmaxf(m, __shfl_xor(m, 1));
        m = fmaxf(m, __shfl_xor(m, 2));
        m = fmaxf(m, __shfl_xor(m, 4));
        m = fmaxf(m, __shfl_xor(m, 8));
        float l = 0.f;
#pragma unroll
        for (int jt = 0; jt < 16; jt++) {
            float pv = __expf(s[jt][r] - m);
            s[jt][r] = pv;
            l += pv;
        }
        l += __shfl_xor(l, 1);
        l += __shfl_xor(l, 2);
        l += __shfl_xor(l, 4);
        l += __shfl_xor(l, 8);
        lsum[r] = l;
    }

#pragma unroll
    for (int jt = 0; jt < 16; jt++)
#pragma unroll
        for (int r = 0; r < 4; r++)
            ps[w][quad * 4 + r][jt * 16 + l15] = bf(s[jt][r]);
    __syncthreads();

    f32x4 z[4] = {};
    const u16* vp = vpT + ((size_t)h * 64 + l15) * 256 + quad * 8;
#pragma unroll
    for (int kj = 0; kj < 8; kj++) {
        s16x8 a = *(const s16x8*)&ps[w][l15][kj * 32 + quad * 8];
#pragma unroll
        for (int et = 0; et < 4; et++) {
            s16x8 b = *(const s16x8*)(vp + et * 16 * 256 + kj * 32);
            z[et] = mfma16(a, b, z[et]);
        }
    }
#pragma unroll
    for (int et = 0; et < 4; et++) {
        int e = et * 16 + l15;
        u16* o = zs + ((size_t)(nbase + quad * 4)) * 1024 + h * 64 + e;
#pragma unroll
        for (int r = 0; r < 4; r++) o[(size_t)r * 1024] = bf(z[et][r] / lsum[r]);
    }
}

// ---- K5: out = zs @ Wo^T, split-K=4 with fp32 atomics -------------------

__global__ __launch_bounds__(256) void out_kernel(
        const u16* __restrict__ zs, const u16* __restrict__ wob,
        float* __restrict__ out) {
    int ks   = blockIdx.x & 3;
    int bm   = blockIdx.x >> 2;
    int lane = threadIdx.x & 63, w = threadIdx.x >> 6;
    int l15  = lane & 15, quad = lane >> 4;
    int row0 = bm * 128 + w * 32;

    const u16* A = zs  + (size_t)(row0 + l15) * 1024 + ks * 256 + quad * 8;
    const u16* B = wob + (size_t)l15 * 1024 + ks * 256 + quad * 8;

    f32x4 acc[2][4] = {};
    for (int k = 0; k < 256; k += 32) {
        s16x8 a0 = *(const s16x8*)(A + k);
        s16x8 a1 = *(const s16x8*)(A + 16 * 1024 + k);
#pragma unroll
        for (int nt = 0; nt < 4; nt++) {
            s16x8 bv = *(const s16x8*)(B + (size_t)nt * 16 * 1024 + k);
            acc[0][nt] = mfma16(a0, bv, acc[0][nt]);
            acc[1][nt] = mfma16(a1, bv, acc[1][nt]);
        }
    }
#pragma unroll
    for (int mt = 0; mt < 2; mt++)
#pragma unroll
        for (int nt = 0; nt < 4; nt++) {
            int e = nt * 16 + l15;
            int n0 = row0 + mt * 16 + quad * 4;
            float* o = out + (size_t)n0 * 64 + e;
#pragma unroll
            for (int r = 0; r < 4; r++) atomicAdd(o + (size_t)r * 64, acc[mt][nt][r]);
        }
}

// ---- launch --------------------------------------------------------------

extern "C" void kernel_launch(void* const* d_in, const int* in_sizes, int n_in,
                              void* d_out, int out_size, void* d_ws, size_t ws_size,
                              hipStream_t stream) {
    const float* x  = (const float*)d_in[0];
    const float* Wq = (const float*)d_in[1];
    const float* bq = (const float*)d_in[2];
    const float* Wk = (const float*)d_in[3];
    const float* bk = (const float*)d_in[4];
    const float* Wv = (const float*)d_in[5];
    const float* bv = (const float*)d_in[6];
    const float* Ew = (const float*)d_in[7];
    const float* Eb = (const float*)d_in[8];
    const float* Fw = (const float*)d_in[9];
    const float* Fb = (const float*)d_in[10];
    const float* Wo = (const float*)d_in[11];

    char* ws = (char*)d_ws;
    u16*   qb   = (u16*)(ws + 0);          // H*N*E bf16            8 MB
    u16*   kT   = (u16*)(ws + 8388608);    // H*E*N bf16            8 MB
    u16*   vT   = (u16*)(ws + 16777216);   // H*E*N bf16            8 MB
    u16*   zsb  = (u16*)(ws + 25165824);   // N*(H*E) bf16          8 MB
    float* accs = (float*)(ws + 33554432); // 16 slices x 2 MB fp32 32 MB
    u16*   kp   = (u16*)(ws + 67108864);   // H*256*64 bf16       0.5 MB
    u16*   vpT  = (u16*)(ws + 67633152);   // H*64*256 bf16       0.5 MB
    u16*   xb   = (u16*)(ws + 68157440);   // N*D bf16              8 MB
    u16*   wb   = (u16*)(ws + 76546048);   // 3*H*E*D bf16          6 MB
    u16*   wob  = (u16*)(ws + 82837504);   // E*(H*E) bf16       128 KB

    hipMemsetAsync(d_out, 0, (size_t)4096 * 64 * sizeof(float), stream);

    cvt_kernel<<<4096, 256, 0, stream>>>(x,  xb, 1048576);
    cvt_kernel<<<1024, 256, 0, stream>>>(Wq, wb,           262144);
    cvt_kernel<<<1024, 256, 0, stream>>>(Wk, wb + 1048576, 262144);
    cvt_kernel<<<1024, 256, 0, stream>>>(Wv, wb + 2097152, 262144);
    cvt_kernel<<<64,   256, 0, stream>>>(Wo, wob, 16384);

    qkv_kernel<<<768, 256, 0, stream>>>(xb, wb, bq, bk, bv, qb, kT, vT);
    kpvp_kernel<<<1024, 256, 0, stream>>>(Ew, Fw, kT, vT, accs);
    packkv_kernel<<<2048, 256, 0, stream>>>(accs, Eb, Fb, kp, vpT);
    attn_kernel<<<1024, 256, 0, stream>>>(qb, kp, vpT, zsb);
    out_kernel<<<128, 256, 0, stream>>>(zsb, wob, (float*)d_out);
}

// Round 6
// 299.378 us; speedup vs baseline: 1.0681x; 1.0398x over previous
//
#include <hip/hip_runtime.h>
#include <hip/hip_bf16.h>

typedef __attribute__((ext_vector_type(4))) float f32x4;
typedef __attribute__((ext_vector_type(8))) short s16x8;
typedef __attribute__((ext_vector_type(4))) short s16x4;
typedef unsigned short u16;

// ---- helpers -------------------------------------------------------------

__device__ __forceinline__ f32x4 mfma16(s16x8 a, s16x8 b, f32x4 c) {
    return __builtin_amdgcn_mfma_f32_16x16x32_bf16(a, b, c, 0, 0, 0);
}

// RNE fp32 -> bf16 (bit trick)
__device__ __forceinline__ u16 bf(float f) {
    union { float f; unsigned u; } x; x.f = f;
    return (u16)((x.u + 0x7fffu + ((x.u >> 16) & 1u)) >> 16);
}
__device__ __forceinline__ unsigned pkbf(float a, float b) {
    union { float f; unsigned u; } x, y; x.f = a; y.f = b;
    unsigned ra = x.u + 0x7fffu + ((x.u >> 16) & 1u);
    unsigned rb = y.u + 0x7fffu + ((y.u >> 16) & 1u);
    return (ra >> 16) | (rb & 0xffff0000u);
}

// async global->LDS, 16B per lane (wave-uniform LDS base + lane*16)
__device__ __forceinline__ void gl_lds16(const u16* g, u16* l) {
    __builtin_amdgcn_global_load_lds(
        (const __attribute__((address_space(1))) unsigned*)g,
        (__attribute__((address_space(3))) unsigned*)l, 16, 0, 0);
}

// ---- K0: merged fp32 -> bf16 convert (x, Wq, Wk, Wv, Wo in one launch) ---

__global__ __launch_bounds__(256) void cvt_all_kernel(
        const float* __restrict__ x,  const float* __restrict__ Wq,
        const float* __restrict__ Wk, const float* __restrict__ Wv,
        const float* __restrict__ Wo,
        u16* __restrict__ xb, u16* __restrict__ wb, u16* __restrict__ wob) {
    int i = blockIdx.x * 256 + threadIdx.x;
    const float* src; u16* dst; int off;
    if (i < 1048576)      { src = x;  dst = xb;            off = i; }
    else if (i < 1310720) { src = Wq; dst = wb;            off = i - 1048576; }
    else if (i < 1572864) { src = Wk; dst = wb + 1048576;  off = i - 1310720; }
    else if (i < 1835008) { src = Wv; dst = wb + 2097152;  off = i - 1572864; }
    else if (i < 1851392) { src = Wo; dst = wob;           off = i - 1835008; }
    else return;
    f32x4 v = ((const f32x4*)src)[off];
    union { s16x4 v; unsigned u[2]; } r;
    r.u[0] = pkbf(v.x, v.y);
    r.u[1] = pkbf(v.z, v.w);
    ((s16x4*)dst)[off] = r.v;
}

// ---- K1: QKV projections, m97-style LDS-staged 128x128 GEMM -------------

__global__ __launch_bounds__(256, 3) void qkv_kernel(
        const u16* __restrict__ xb, const u16* __restrict__ wb,
        const float* __restrict__ bq, const float* __restrict__ bk,
        const float* __restrict__ bv,
        u16* __restrict__ qo, u16* __restrict__ kTo, u16* __restrict__ vTo) {
    __shared__ u16 As[128 * 32];
    __shared__ u16 Bs[128 * 32];
    int bx   = blockIdx.x % 24;
    int by   = blockIdx.x / 24;
    int tid  = threadIdx.x;
    int lane = tid & 63, w = tid >> 6;
    int l15  = lane & 15, quad = lane >> 4;
    int wr   = w >> 1, wc = w & 1;

    const u16* Ag = xb + (size_t)(by * 128 + (tid >> 2)) * 1024 + (tid & 3) * 8;
    const u16* Bg = wb + (size_t)(bx * 128 + (tid >> 2)) * 1024 + (tid & 3) * 8;
    u16* Al = As + tid * 8;
    u16* Bl = Bs + tid * 8;

    const u16* abase = As + (wr * 64 + l15) * 32 + quad * 8;
    const u16* bbase = Bs + (wc * 64 + l15) * 32 + quad * 8;

    f32x4 acc[4][4] = {};
    for (int k0 = 0; k0 < 1024; k0 += 32) {
        gl_lds16(Ag + k0, Al);
        gl_lds16(Ag + 64 * 1024 + k0, Al + 64 * 32);
        gl_lds16(Bg + k0, Bl);
        gl_lds16(Bg + 64 * 1024 + k0, Bl + 64 * 32);
        __syncthreads();
        s16x8 a[4], b[4];
#pragma unroll
        for (int mi = 0; mi < 4; mi++) a[mi] = *(const s16x8*)(abase + mi * 16 * 32);
#pragma unroll
        for (int nj = 0; nj < 4; nj++) b[nj] = *(const s16x8*)(bbase + nj * 16 * 32);
#pragma unroll
        for (int mi = 0; mi < 4; mi++)
#pragma unroll
            for (int nj = 0; nj < 4; nj++) acc[mi][nj] = mfma16(a[mi], b[nj], acc[mi][nj]);
        __syncthreads();
    }

    int fblk = (bx * 128 + wc * 64) >> 6;
    int mat  = fblk >> 4, h = fblk & 15;
    const float* bias = (mat == 0) ? bq : (mat == 1 ? bk : bv);
#pragma unroll
    for (int nj = 0; nj < 4; nj++) {
        int e = nj * 16 + l15;
        float bb = bias[h * 64 + e];
#pragma unroll
        for (int mi = 0; mi < 4; mi++) {
            int n0 = by * 128 + wr * 64 + mi * 16 + quad * 4;
            f32x4 c = acc[mi][nj];
            if (mat == 0) {
                u16* p = qo + ((size_t)h * 4096 + n0) * 64 + e;
#pragma unroll
                for (int r = 0; r < 4; r++) p[(size_t)r * 64] = bf(c[r] + bb);
            } else {
                u16* p = (mat == 1 ? kTo : vTo) + ((size_t)h * 64 + e) * 4096 + n0;
                union { s16x4 v; u16 s[4]; } pk;
#pragma unroll
                for (int r = 0; r < 4; r++) pk.s[r] = bf(c[r] + bb);
                *(s16x4*)p = pk.v;
            }
        }
    }
}

// ---- K2: kp/vp — M=256 tiles (full j), split-K=16, no atomics -----------
// grid: b = (p*16 + h)*16 + ks  (512 blocks, 2/CU)
// block: M=256 (j), N=64 (e), K-chunk=256 in 8 stages of BK=32.
// 16 MFMA/wave/stage (2x round-5) to amortize the barrier-pair latency.
// A (fp32) staged coalesced + cvt + ds_write, pitch 40; B via gl_lds16.

__global__ __launch_bounds__(256, 2) void kpvp_kernel(
        const float* __restrict__ Ew, const float* __restrict__ Fw,
        const u16* __restrict__ kT, const u16* __restrict__ vT,
        float* __restrict__ accs) {
    __shared__ u16 As[256 * 40];   // 20 KB
    __shared__ u16 Bs[64 * 32];    // 4 KB
    int b    = blockIdx.x;
    int ks   = b & 15, h = (b >> 4) & 15, p = b >> 8;
    int tid  = threadIdx.x;
    int lane = tid & 63, w = tid >> 6;
    int l15  = lane & 15, quad = lane >> 4;

    // A: 8 lanes per 128B row-chunk (32 fp32), 32 rows/pass, 8 passes
    const float* Ag = (p ? Fw : Ew)
        + (size_t)(h * 256 + (tid >> 3)) * 4096 + ks * 256 + (tid & 7) * 4;
    const u16* Bg = (p ? vT : kT)
        + ((size_t)h * 64 + (tid >> 2)) * 4096 + ks * 256 + (tid & 3) * 8;
    u16* Aw = As + (tid >> 3) * 40 + (tid & 7) * 4;
    u16* Bl = Bs + tid * 8;

    const u16* abase = As + (w * 64 + l15) * 40 + quad * 8;  // wave w: rows w*64..
    const u16* bbase = Bs + l15 * 32 + quad * 8;             // all waves share B

    f32x4 acc[4][4] = {};
    for (int s = 0; s < 8; s++) {
        int kk = s * 32;
        gl_lds16(Bg + kk, Bl);
#pragma unroll
        for (int pr = 0; pr < 8; pr++) {
            f32x4 v = *(const f32x4*)(Ag + (size_t)pr * 32 * 4096 + kk);
            union { s16x4 q; unsigned u[2]; } rr;
            rr.u[0] = pkbf(v.x, v.y);
            rr.u[1] = pkbf(v.z, v.w);
            *(s16x4*)(Aw + pr * 32 * 40) = rr.q;
        }
        __syncthreads();
        s16x8 a[4], bb2[4];
#pragma unroll
        for (int mt = 0; mt < 4; mt++) a[mt] = *(const s16x8*)(abase + mt * 16 * 40);
#pragma unroll
        for (int nt = 0; nt < 4; nt++) bb2[nt] = *(const s16x8*)(bbase + nt * 16 * 32);
#pragma unroll
        for (int mt = 0; mt < 4; mt++)
#pragma unroll
            for (int nt = 0; nt < 4; nt++)
                acc[mt][nt] = mfma16(a[mt], bb2[nt], acc[mt][nt]);
        __syncthreads();
    }

    size_t base = (size_t)ks * 524288
        + ((size_t)(p * 16 + h) * 256 + w * 64 + quad * 4) * 64 + l15;
#pragma unroll
    for (int mt = 0; mt < 4; mt++)
#pragma unroll
        for (int nt = 0; nt < 4; nt++)
#pragma unroll
            for (int r = 0; r < 4; r++)
                accs[base + (size_t)(mt * 16 + r) * 64 + nt * 16] = acc[mt][nt][r];
}

// ---- K3: reduce 16 slices + bias + pack ---------------------------------

__global__ __launch_bounds__(256) void packkv_kernel(
        const float* __restrict__ accs, const float* __restrict__ Eb,
        const float* __restrict__ Fb, u16* __restrict__ kp, u16* __restrict__ vpT) {
    int idx = blockIdx.x * 256 + threadIdx.x;
    float v = 0.f;
#pragma unroll
    for (int s = 0; s < 16; s++) v += accs[idx + (size_t)s * 524288];
    int p = idx >> 18, h = (idx >> 14) & 15, j = (idx >> 6) & 255, e = idx & 63;
    if (p == 0) {
        v += Eb[h * 256 + j];
        kp[((size_t)(h * 256 + j)) * 64 + e] = bf(v * 0.125f);  // fold 1/sqrt(64)
    } else {
        v += Fb[h * 256 + j];
        vpT[((size_t)(h * 64 + e)) * 256 + j] = bf(v);
    }
}

// ---- K4: attention: score -> softmax -> PV ------------------------------

__global__ __launch_bounds__(256) void attn_kernel(
        const u16* __restrict__ q, const u16* __restrict__ kp,
        const u16* __restrict__ vpT, u16* __restrict__ zs) {
    __shared__ u16 ps[4][16][256];
    int bm   = blockIdx.x & 63, h = blockIdx.x >> 6;
    int lane = threadIdx.x & 63, w = threadIdx.x >> 6;
    int l15  = lane & 15, quad = lane >> 4;
    int nbase = bm * 64 + w * 16;

    f32x4 s[16] = {};
    const u16* qp  = q  + ((size_t)h * 4096 + nbase + l15) * 64 + quad * 8;
    const u16* kpp = kp + ((size_t)h * 256 + l15) * 64 + quad * 8;
#pragma unroll
    for (int e0 = 0; e0 < 64; e0 += 32) {
        s16x8 a = *(const s16x8*)(qp + e0);
#pragma unroll
        for (int jt = 0; jt < 16; jt++) {
            s16x8 b = *(const s16x8*)(kpp + jt * 16 * 64 + e0);
            s[jt] = mfma16(a, b, s[jt]);
        }
    }

    float lsum[4];
#pragma unroll
    for (int r = 0; r < 4; r++) {
        float m = s[0][r];
#pragma unroll
        for (int jt = 1; jt < 16; jt++) m = fmaxf(m, s[jt][r]);
        m = fmaxf(m, __shfl_xor(m, 1));
        m = fmaxf(m, __shfl_xor(m, 2));
        m = fmaxf(m, __shfl_xor(m, 4));
        m = fmaxf(m, __shfl_xor(m, 8));
        float l = 0.f;
#pragma unroll
        for (int jt = 0; jt < 16; jt++) {
            float pv = __expf(s[jt][r] - m);
            s[jt][r] = pv;
            l += pv;
        }
        l += __shfl_xor(l, 1);
        l += __shfl_xor(l, 2);
        l += __shfl_xor(l, 4);
        l += __shfl_xor(l, 8);
        lsum[r] = l;
    }

#pragma unroll
    for (int jt = 0; jt < 16; jt++)
#pragma unroll
        for (int r = 0; r < 4; r++)
            ps[w][quad * 4 + r][jt * 16 + l15] = bf(s[jt][r]);
    __syncthreads();

    f32x4 z[4] = {};
    const u16* vp = vpT + ((size_t)h * 64 + l15) * 256 + quad * 8;
#pragma unroll
    for (int kj = 0; kj < 8; kj++) {
        s16x8 a = *(const s16x8*)&ps[w][l15][kj * 32 + quad * 8];
#pragma unroll
        for (int et = 0; et < 4; et++) {
            s16x8 b = *(const s16x8*)(vp + et * 16 * 256 + kj * 32);
            z[et] = mfma16(a, b, z[et]);
        }
    }
#pragma unroll
    for (int et = 0; et < 4; et++) {
        int e = et * 16 + l15;
        u16* o = zs + ((size_t)(nbase + quad * 4)) * 1024 + h * 64 + e;
#pragma unroll
        for (int r = 0; r < 4; r++) o[(size_t)r * 1024] = bf(z[et][r] / lsum[r]);
    }
}

// ---- K5: out = zs @ Wo^T, split-K=4, disjoint slices (no atomics) -------

__global__ __launch_bounds__(256) void out_kernel(
        const u16* __restrict__ zs, const u16* __restrict__ wob,
        float* __restrict__ oslice) {
    int ks   = blockIdx.x & 3;
    int bm   = blockIdx.x >> 2;
    int lane = threadIdx.x & 63, w = threadIdx.x >> 6;
    int l15  = lane & 15, quad = lane >> 4;
    int row0 = bm * 128 + w * 32;

    const u16* A = zs  + (size_t)(row0 + l15) * 1024 + ks * 256 + quad * 8;
    const u16* B = wob + (size_t)l15 * 1024 + ks * 256 + quad * 8;

    f32x4 acc[2][4] = {};
    for (int k = 0; k < 256; k += 32) {
        s16x8 a0 = *(const s16x8*)(A + k);
        s16x8 a1 = *(const s16x8*)(A + 16 * 1024 + k);
#pragma unroll
        for (int nt = 0; nt < 4; nt++) {
            s16x8 bv = *(const s16x8*)(B + (size_t)nt * 16 * 1024 + k);
            acc[0][nt] = mfma16(a0, bv, acc[0][nt]);
            acc[1][nt] = mfma16(a1, bv, acc[1][nt]);
        }
    }
    float* os = oslice + (size_t)ks * 262144;
#pragma unroll
    for (int mt = 0; mt < 2; mt++)
#pragma unroll
        for (int nt = 0; nt < 4; nt++) {
            int e = nt * 16 + l15;
            int n0 = row0 + mt * 16 + quad * 4;
            float* o = os + (size_t)n0 * 64 + e;
#pragma unroll
            for (int r = 0; r < 4; r++) o[(size_t)r * 64] = acc[mt][nt][r];
        }
}

__global__ __launch_bounds__(256) void outred_kernel(
        const float* __restrict__ oslice, float* __restrict__ out) {
    int i = blockIdx.x * 256 + threadIdx.x;   // 262144 total
    out[i] = oslice[i] + oslice[i + 262144] + oslice[i + 524288] + oslice[i + 786432];
}

// ---- launch --------------------------------------------------------------

extern "C" void kernel_launch(void* const* d_in, const int* in_sizes, int n_in,
                              void* d_out, int out_size, void* d_ws, size_t ws_size,
                              hipStream_t stream) {
    const float* x  = (const float*)d_in[0];
    const float* Wq = (const float*)d_in[1];
    const float* bq = (const float*)d_in[2];
    const float* Wk = (const float*)d_in[3];
    const float* bk = (const float*)d_in[4];
    const float* Wv = (const float*)d_in[5];
    const float* bv = (const float*)d_in[6];
    const float* Ew = (const float*)d_in[7];
    const float* Eb = (const float*)d_in[8];
    const float* Fw = (const float*)d_in[9];
    const float* Fb = (const float*)d_in[10];
    const float* Wo = (const float*)d_in[11];

    char* ws = (char*)d_ws;
    u16*   qb   = (u16*)(ws + 0);          // H*N*E bf16            8 MB
    u16*   kT   = (u16*)(ws + 8388608);    // H*E*N bf16            8 MB
    u16*   vT   = (u16*)(ws + 16777216);   // H*E*N bf16            8 MB
    u16*   zsb  = (u16*)(ws + 25165824);   // N*(H*E) bf16          8 MB
    float* accs = (float*)(ws + 33554432); // 16 slices x 2 MB fp32 32 MB (reused as oslice)
    u16*   kp   = (u16*)(ws + 67108864);   // H*256*64 bf16       0.5 MB
    u16*   vpT  = (u16*)(ws + 67633152);   // H*64*256 bf16       0.5 MB
    u16*   xb   = (u16*)(ws + 68157440);   // N*D bf16              8 MB
    u16*   wb   = (u16*)(ws + 76546048);   // 3*H*E*D bf16          6 MB
    u16*   wob  = (u16*)(ws + 82837504);   // E*(H*E) bf16       128 KB

    cvt_all_kernel<<<7232, 256, 0, stream>>>(x, Wq, Wk, Wv, Wo, xb, wb, wob);
    qkv_kernel<<<768, 256, 0, stream>>>(xb, wb, bq, bk, bv, qb, kT, vT);
    kpvp_kernel<<<512, 256, 0, stream>>>(Ew, Fw, kT, vT, accs);
    packkv_kernel<<<2048, 256, 0, stream>>>(accs, Eb, Fb, kp, vpT);
    attn_kernel<<<1024, 256, 0, stream>>>(qb, kp, vpT, zsb);
    out_kernel<<<128, 256, 0, stream>>>(zsb, wob, (float*)accs);   // accs free -> oslice
    outred_kernel<<<1024, 256, 0, stream>>>((const float*)accs, (float*)d_out);
}